// Round 12
// baseline (140.890 us; speedup 1.0000x reference)
//
#include <hip/hip_runtime.h>

#define DIM 1024
#define SEQ 2048
#define BATCH 2
#define NHEADS 16
#define HD 64
#define ROWS (BATCH * SEQ) // 4096

typedef __bf16 bf16x8 __attribute__((ext_vector_type(8)));
typedef __bf16 bf16x4 __attribute__((ext_vector_type(4)));
typedef float f32x4 __attribute__((ext_vector_type(4)));
typedef float f32x16 __attribute__((ext_vector_type(16)));
typedef unsigned u32x4 __attribute__((ext_vector_type(4)));

__device__ __forceinline__ f32x4 f4zero() {
    f32x4 z = {0.f, 0.f, 0.f, 0.f};
    return z;
}

__device__ __forceinline__ unsigned cvtpk(float lo, float hi) {
    unsigned r;
    asm("v_cvt_pk_bf16_f32 %0, %1, %2" : "=v"(r) : "v"(lo), "v"(hi));
    return r;
}

__device__ __forceinline__ void pl32swap(unsigned& a, unsigned& b) {
    asm volatile("v_permlane32_swap_b32 %0, %1" : "+v"(a), "+v"(b));
}

__device__ __forceinline__ float fexp2(float x) {
    float r;
    asm("v_exp_f32 %0, %1" : "=v"(r) : "v"(x));
    return r;
}

#define GLOAD_LDS16(g, l)                                                                  \
    __builtin_amdgcn_global_load_lds((const __attribute__((address_space(1))) void*)(g),   \
                                     (__attribute__((address_space(3))) void*)(l), 16, 0, 0)

// ---------------- RMSNorm -> bf16 ----------------
__global__ __launch_bounds__(256) void rmsnorm_bf16(const float* __restrict__ x,
                                                    const float* __restrict__ w,
                                                    __bf16* __restrict__ xn) {
    int row = blockIdx.x;
    int t = threadIdx.x;
    float4 v = ((const float4*)(x + (size_t)row * DIM))[t];
    float ss = v.x * v.x + v.y * v.y + v.z * v.z + v.w * v.w;
#pragma unroll
    for (int off = 1; off < 64; off <<= 1) ss += __shfl_xor(ss, off);
    __shared__ float red[4];
    if ((t & 63) == 0) red[t >> 6] = ss;
    __syncthreads();
    ss = red[0] + red[1] + red[2] + red[3];
    float scale = rsqrtf(ss * (1.0f / DIM) + 1e-5f);
    float4 wv = ((const float4*)w)[t];
    bf16x4 o;
    o[0] = (__bf16)(v.x * scale * wv.x);
    o[1] = (__bf16)(v.y * scale * wv.y);
    o[2] = (__bf16)(v.z * scale * wv.z);
    o[3] = (__bf16)(v.w * scale * wv.w);
    *(bf16x4*)(xn + (size_t)row * DIM + t * 4) = o;
}

// ---------------- Weight convert + transpose: W[k][n] f32 -> Wt[n][k] bf16 ----------------
__global__ __launch_bounds__(256) void wcvt_kernel(const float* __restrict__ Wq,
                                                   const float* __restrict__ Wk,
                                                   const float* __restrict__ Wv,
                                                   const float* __restrict__ Wo,
                                                   __bf16* tq, __bf16* tk, __bf16* tv, __bf16* to_) {
    int z = blockIdx.z;
    const float* W = z == 0 ? Wq : z == 1 ? Wk : z == 2 ? Wv : Wo;
    __bf16* T = z == 0 ? tq : z == 1 ? tk : z == 2 ? tv : to_;
    __shared__ float tile[32][33];
    int n0 = blockIdx.x * 32, k0 = blockIdx.y * 32;
    int tx = threadIdx.x & 31, ty = threadIdx.x >> 5;
#pragma unroll
    for (int j = 0; j < 32; j += 8) tile[ty + j][tx] = W[(size_t)(k0 + ty + j) * DIM + n0 + tx];
    __syncthreads();
#pragma unroll
    for (int j = 0; j < 32; j += 8)
        T[(size_t)(n0 + ty + j) * DIM + k0 + tx] = (__bf16)tile[tx][ty + j];
}

// ---------------- RoPE table ----------------
__global__ __launch_bounds__(256) void rope_table_kernel(float* __restrict__ cosT,
                                                         float* __restrict__ sinT) {
    int idx = blockIdx.x * 256 + threadIdx.x; // SEQ*32
    int s = idx >> 5, i = idx & 31;
    float e = (2.0f * (float)i) / 64.0f;
    float theta = 1.0f / powf(1000000.0f, e);
    float ang = (float)s * theta;
    cosT[idx] = cosf(ang);
    sinT[idx] = sinf(ang);
}

// ---------------- MFMA GEMM core (m97-style), acc left in registers ----------------
__device__ __forceinline__ void gemm_core(const __bf16* __restrict__ A,
                                          const __bf16* __restrict__ Bt,
                                          int K, __bf16* As, __bf16* Bs,
                                          f32x4 (&acc)[4][4], int row0, int col0) {
    int tid = threadIdx.x;
    int w = tid >> 6, l = tid & 63, l15 = l & 15, g = l >> 4;
    int wr = (w >> 1) << 6, wc = (w & 1) << 6;

    int sr0 = tid >> 2;
    int sr1 = 64 + (tid >> 2);
    int lc0 = (((tid & 3) ^ ((tid >> 3) & 3)) << 3); // swizzled source chunk
    const __bf16* gA0 = A + (size_t)(row0 + sr0) * K + lc0;
    const __bf16* gA1 = A + (size_t)(row0 + sr1) * K + lc0;
    const __bf16* gB0 = Bt + (size_t)(col0 + sr0) * K + lc0;
    const __bf16* gB1 = Bt + (size_t)(col0 + sr1) * K + lc0;
    __bf16* lA0 = As + w * 512;
    __bf16* lA1 = As + 2048 + w * 512;
    __bf16* lB0 = Bs + w * 512;
    __bf16* lB1 = Bs + 2048 + w * 512;

    int rca = ((g ^ ((l15 >> 1) & 3)) << 3); // swizzled read chunk

#pragma unroll
    for (int i = 0; i < 4; ++i)
#pragma unroll
        for (int j = 0; j < 4; ++j) acc[i][j] = f4zero();

    for (int k0 = 0; k0 < K; k0 += 32) {
        __syncthreads();
        GLOAD_LDS16(gA0 + k0, lA0);
        GLOAD_LDS16(gA1 + k0, lA1);
        GLOAD_LDS16(gB0 + k0, lB0);
        GLOAD_LDS16(gB1 + k0, lB1);
        __syncthreads();

        bf16x8 af[4], bfr[4];
#pragma unroll
        for (int i = 0; i < 4; ++i) af[i] = *(const bf16x8*)&As[(wr + i * 16 + l15) * 32 + rca];
#pragma unroll
        for (int j = 0; j < 4; ++j) bfr[j] = *(const bf16x8*)&Bs[(wc + j * 16 + l15) * 32 + rca];
        __builtin_amdgcn_s_setprio(1);
#pragma unroll
        for (int i = 0; i < 4; ++i)
#pragma unroll
            for (int j = 0; j < 4; ++j)
                acc[i][j] = __builtin_amdgcn_mfma_f32_16x16x32_bf16(af[i], bfr[j], acc[i][j], 0, 0, 0);
        __builtin_amdgcn_s_setprio(0);
    }
}

// Fused QKV GEMM, 768 blocks. Outputs written in MFMA FRAGMENT ORDER:
//  Q/K: f[bh][s32][g][lane][e], lane=(s&31)|hi<<5, dd=g*16+hi*8+e (RoPE fused).
//  V:   vf[bh][t32][half][kk][lane][e], lane=(d&31)|((s>>3)&1)<<5, s=t32*32+kk*16+hi*8+e.
__global__ __launch_bounds__(256) void gemm_qkv_kernel(const __bf16* __restrict__ xn,
                                                       const __bf16* __restrict__ wq,
                                                       const __bf16* __restrict__ wk,
                                                       const __bf16* __restrict__ wv,
                                                       __bf16* __restrict__ qf,
                                                       __bf16* __restrict__ kf,
                                                       __bf16* __restrict__ vf,
                                                       const float* __restrict__ cosT,
                                                       const float* __restrict__ sinT) {
    __shared__ __bf16 As[128 * 32];
    __shared__ __bf16 Bs[128 * 32];
    int bid = blockIdx.x;
    int tid = threadIdx.x;
    int w = tid >> 6, l = tid & 63, l15 = l & 15, gq = l >> 4;
    int wr = (w >> 1) << 6, wc = (w & 1) << 6;
    f32x4 acc[4][4];

    if (bid < 512) {
        int z = bid >> 8, t = bid & 255;
        int col0 = (t & 7) << 7, row0 = (t >> 3) << 7;
        gemm_core(xn, z ? wk : wq, DIM, As, Bs, acc, row0, col0);
        __bf16* F = z ? kf : qf;
        int colbase = col0 + wc;
#pragma unroll
        for (int i = 0; i < 4; ++i) {
#pragma unroll
            for (int r = 0; r < 4; ++r) {
                int row = row0 + wr + i * 16 + gq * 4 + r;
                int s = row & (SEQ - 1);
                int bb = row >> 11;
#pragma unroll
                for (int j = 0; j < 2; ++j) {
                    float c = cosT[s * 32 + j * 16 + l15];
                    float sn = sinT[s * 32 + j * 16 + l15];
                    float x1 = acc[i][j][r], x2 = acc[i][j + 2][r];
#pragma unroll
                    for (int p = 0; p < 2; ++p) {
                        int col = colbase + (j + 2 * p) * 16 + l15;
                        float v = p ? (x1 * sn + x2 * c) : (x1 * c - x2 * sn);
                        int hh = col >> 6, dd = col & 63;
                        size_t tb = (size_t)(bb * 16 + hh) * 64 + (s >> 5);
                        tb = tb * 4 + ((dd >> 4) & 3);
                        int lane = (s & 31) | (((dd >> 3) & 1) << 5);
                        size_t idx = (tb * 64 + lane) * 8 + (dd & 7);
                        F[idx] = (__bf16)v;
                    }
                }
            }
        }
    } else {
        int t = bid - 512;           // 256 blocks: [batch 2][n-blocks 8][s-blocks 16]
        int b = t >> 7, r7 = t & 127;
        int row0 = (r7 >> 4) << 7;   // n
        int col0 = (r7 & 15) << 7;   // s
        gemm_core(wv, xn + (size_t)b * SEQ * DIM, DIM, As, Bs, acc, row0, col0);
#pragma unroll
        for (int i = 0; i < 4; ++i) {
#pragma unroll
            for (int r = 0; r < 4; ++r) {
                int rowN = row0 + wr + i * 16 + gq * 4 + r;
                int hh = rowN >> 6, dd = rowN & 63;
#pragma unroll
                for (int j = 0; j < 4; ++j) {
                    int col = col0 + wc + j * 16 + l15; // s
                    size_t tb = (size_t)(b * 16 + hh) * 64 + (col >> 5);
                    tb = tb * 2 + (dd >> 5);
                    tb = tb * 2 + ((col >> 4) & 1);
                    int lane = (dd & 31) | (((col >> 3) & 1) << 5);
                    size_t idx = (tb * 64 + lane) * 8 + (col & 7);
                    vf[idx] = (__bf16)acc[i][j][r];
                }
            }
        }
    }
}

__global__ __launch_bounds__(256) void gemm_out_kernel(const __bf16* __restrict__ ctx,
                                                       const __bf16* __restrict__ wo,
                                                       float* __restrict__ out) {
    __shared__ __bf16 As[128 * 32];
    __shared__ __bf16 Bs[128 * 32];
    int row0 = (int)blockIdx.y << 7, col0 = (int)blockIdx.x << 7;
    f32x4 acc[4][4];
    gemm_core(ctx, wo, DIM, As, Bs, acc, row0, col0);
    int tid = threadIdx.x;
    int w = tid >> 6, l = tid & 63, l15 = l & 15, g = l >> 4;
    int wr = (w >> 1) << 6, wc = (w & 1) << 6;
#pragma unroll
    for (int i = 0; i < 4; ++i)
#pragma unroll
        for (int j = 0; j < 4; ++j)
#pragma unroll
            for (int r = 0; r < 4; ++r) {
                int row = row0 + wr + i * 16 + g * 4 + r;
                int col = col0 + wc + j * 16 + l15;
                out[(size_t)row * DIM + col] = acc[i][j][r];
            }
}

// ---------------- Barrier-free split-KV attention on fragment-major buffers ----------------
// Grid (32 bh, 24) x 256 thr = 4 independent waves/block; 96 slots/bh (chunks of 1024 KV
// positions, <=2 per 32-row q-strip). All operand loads are coalesced 1KB fragment reads.
// No LDS, no barriers; ping-pong K prefetch; per-wave online softmax (verified r7 math).
__global__ __launch_bounds__(256, 3) void attn_mfma_kernel(const __bf16* __restrict__ qf,
                                                           const __bf16* __restrict__ kf,
                                                           const __bf16* __restrict__ vf,
                                                           __bf16* __restrict__ part_O,
                                                           float* __restrict__ part_ml) {
    int bh = blockIdx.x;
    int tid = threadIdx.x, wvx = tid >> 6, l = tid & 63;
    int wslot = (int)blockIdx.y * 4 + wvx;
    int slot = 95 - wslot; // heavy first
    int qp, ci;
    if (slot < 32) {
        qp = slot;
        ci = 0;
    } else {
        int t = slot - 32;
        qp = 32 + (t >> 1);
        ci = t & 1;
    }
    int rem = qp - (ci << 5);
    int ntiles = rem < 32 ? rem + 1 : 32;
    int dtile = rem < 32 ? rem : -1;
    int t0 = ci << 5;

    int l31 = l & 31, hi = l >> 5;
    int qrow = qp * 32 + l31;

    // Q fragments (coalesced), pre-scaled by 0.125*log2(e)
    bf16x8 qfr[4];
    {
        const __bf16* qp_ = qf + ((size_t)bh * 64 + qp) * 2048 + (size_t)l * 8;
        const float c2 = 0.125f * 1.44269504f;
#pragma unroll
        for (int g = 0; g < 4; ++g) {
            bf16x8 tq = *(const bf16x8*)(qp_ + g * 512);
#pragma unroll
            for (int e = 0; e < 8; ++e) qfr[g][e] = (__bf16)((float)tq[e] * c2);
        }
    }

    const __bf16* kfp = kf + ((size_t)bh * 64 + t0) * 2048 + (size_t)l * 8;
    const __bf16* vfp = vf + ((size_t)bh * 64 + t0) * 2048 + (size_t)l * 8;

    f32x16 oA, oB;
#pragma unroll
    for (int r = 0; r < 16; ++r) {
        oA[r] = 0.f;
        oB[r] = 0.f;
    }
    float m_run = -1e30f, l_run = 0.f;

    bf16x8 ka[4], kb[4];
#pragma unroll
    for (int g = 0; g < 4; ++g) ka[g] = *(const bf16x8*)(kfp + g * 512);

    auto tile_body = [&](bf16x8 (&kcur)[4], bf16x8 (&knxt)[4], int st) {
        if (st + 1 < ntiles) { // prefetch next K tile (coalesced)
            const __bf16* kn = kfp + (size_t)(st + 1) * 2048;
#pragma unroll
            for (int g = 0; g < 4; ++g) knxt[g] = *(const bf16x8*)(kn + g * 512);
        }
        const __bf16* vp = vfp + (size_t)st * 2048; // V frags, consumed after softmax
        bf16x8 v00 = *(const bf16x8*)(vp);
        bf16x8 v01 = *(const bf16x8*)(vp + 512);
        bf16x8 v10 = *(const bf16x8*)(vp + 1024);
        bf16x8 v11 = *(const bf16x8*)(vp + 1536);

        // S^T = mfma(K, Q): rows = 32 k-pos of this tile, cols = q (lane&31)
        f32x16 sa;
#pragma unroll
        for (int r = 0; r < 16; ++r) sa[r] = 0.f;
        __builtin_amdgcn_s_setprio(1);
#pragma unroll
        for (int g = 0; g < 4; ++g)
            sa = __builtin_amdgcn_mfma_f32_32x32x16_bf16(kcur[g], qfr[g], sa, 0, 0, 0);
        __builtin_amdgcn_s_setprio(0);

        if (st == dtile) { // causal mask on the diagonal tile
            int s0 = (t0 + st) << 5;
#pragma unroll
            for (int r = 0; r < 16; ++r) {
                int kg = s0 + (r & 3) + 8 * (r >> 2) + 4 * hi;
                if (kg > qrow) sa[r] = -1e30f;
            }
        }

        // online softmax (exp2 domain), defer-max THR=10; native v_exp_f32
        float mx[8];
#pragma unroll
        for (int r = 0; r < 8; ++r) mx[r] = fmaxf(sa[r], sa[r + 8]);
#pragma unroll
        for (int r = 0; r < 4; ++r) mx[r] = fmaxf(mx[r], mx[r + 4]);
        float lmax = fmaxf(fmaxf(mx[0], mx[1]), fmaxf(mx[2], mx[3]));
        if (!__all(lmax <= m_run + 10.0f)) {
            float omax = fmaxf(lmax, __shfl_xor(lmax, 32));
            float m_new = fmaxf(m_run, omax);
            float alpha = fexp2(m_run - m_new);
            l_run *= alpha;
#pragma unroll
            for (int r = 0; r < 16; ++r) {
                oA[r] *= alpha;
                oB[r] *= alpha;
            }
            m_run = m_new;
        }
#pragma unroll
        for (int r = 0; r < 16; ++r) sa[r] = fexp2(sa[r] - m_run);
        float s8[8];
#pragma unroll
        for (int r = 0; r < 8; ++r) s8[r] = sa[r] + sa[r + 8];
#pragma unroll
        for (int r = 0; r < 4; ++r) s8[r] += s8[r + 4];
        float ls = (s8[0] + s8[1]) + (s8[2] + s8[3]);
        l_run += ls + __shfl_xor(ls, 32);

        // pack P -> bf16 B-frags pa0 (k 0..15), pa1 (k 16..31)
        unsigned a0 = cvtpk(sa[0], sa[1]), b0 = cvtpk(sa[4], sa[5]);
        pl32swap(a0, b0);
        unsigned c0 = cvtpk(sa[2], sa[3]), d0 = cvtpk(sa[6], sa[7]);
        pl32swap(c0, d0);
        u32x4 t4a = {a0, c0, b0, d0};
        bf16x8 pa0 = __builtin_bit_cast(bf16x8, t4a);
        unsigned a1 = cvtpk(sa[8], sa[9]), b1 = cvtpk(sa[12], sa[13]);
        pl32swap(a1, b1);
        unsigned c1 = cvtpk(sa[10], sa[11]), d1 = cvtpk(sa[14], sa[15]);
        pl32swap(c1, d1);
        u32x4 t4b = {a1, c1, b1, d1};
        bf16x8 pa1 = __builtin_bit_cast(bf16x8, t4b);

        // O^T += mfma(V^T, P)
        __builtin_amdgcn_s_setprio(1);
        oA = __builtin_amdgcn_mfma_f32_32x32x16_bf16(v00, pa0, oA, 0, 0, 0);
        oA = __builtin_amdgcn_mfma_f32_32x32x16_bf16(v01, pa1, oA, 0, 0, 0);
        oB = __builtin_amdgcn_mfma_f32_32x32x16_bf16(v10, pa0, oB, 0, 0, 0);
        oB = __builtin_amdgcn_mfma_f32_32x32x16_bf16(v11, pa1, oB, 0, 0, 0);
        __builtin_amdgcn_s_setprio(0);
    };

    int st = 0;
    while (st < ntiles) {
        tile_body(ka, kb, st);
        ++st;
        if (st >= ntiles) break;
        tile_body(kb, ka, st);
        ++st;
    }

    // write unnormalized partial: O bf16 [slot][32 q][64 d], m/l f32 [slot][2][32]
    int gslot = bh * 96 + slot;
    __bf16* po = part_O + (size_t)gslot * 2048 + l31 * 64;
#pragma unroll
    for (int rr = 0; rr < 16; rr += 4) {
        int d0 = 8 * (rr >> 2) + 4 * hi;
        uint2 pA = {cvtpk(oA[rr], oA[rr + 1]), cvtpk(oA[rr + 2], oA[rr + 3])};
        uint2 pB = {cvtpk(oB[rr], oB[rr + 1]), cvtpk(oB[rr + 2], oB[rr + 3])};
        *(uint2*)&po[d0] = pA;
        *(uint2*)&po[32 + d0] = pB;
    }
    if (hi == 0) {
        part_ml[(size_t)gslot * 64 + l31] = m_run;
        part_ml[(size_t)gslot * 64 + 32 + l31] = l_run;
    }
}

// ---------------- Combine split-KV partials -> ctx (row-major) ----------------
__global__ __launch_bounds__(128) void attn_combine_kernel(const __bf16* __restrict__ part_O,
                                                           const float* __restrict__ part_ml,
                                                           __bf16* __restrict__ ctx) {
    int bh = blockIdx.x, qp = blockIdx.y;
    int b = bh >> 4, h = bh & 15;
    int nch = 1 + (qp >> 5);
    int base = qp < 32 ? qp : 32 + 2 * (qp - 32);
    size_t so = (size_t)bh * 96 + base;
    int t = threadIdx.x;
    int row = t >> 2, dseg = (t & 3) << 4;

    float mv0 = part_ml[so * 64 + row];
    float mv1 = -1e30f;
    if (nch > 1) mv1 = part_ml[(so + 1) * 64 + row];
    float mmax = fmaxf(mv0, mv1);

    float acc[16];
#pragma unroll
    for (int e = 0; e < 16; ++e) acc[e] = 0.f;
    float lsum = 0.f;

#pragma unroll 2
    for (int i = 0; i < 2; ++i) {
        if (i >= nch) break;
        float mi = i == 0 ? mv0 : mv1;
        float wsc = fexp2(mi - mmax);
        lsum += wsc * part_ml[(so + i) * 64 + 32 + row];
        const __bf16* po = part_O + (so + i) * 2048 + row * 64 + dseg;
        bf16x8 a = *(const bf16x8*)po;
        bf16x8 b2 = *(const bf16x8*)(po + 8);
#pragma unroll
        for (int e = 0; e < 8; ++e) {
            acc[e] += wsc * (float)a[e];
            acc[8 + e] += wsc * (float)b2[e];
        }
    }

    float inv = 1.0f / lsum;
    bf16x8 oa, ob;
#pragma unroll
    for (int e = 0; e < 8; ++e) {
        oa[e] = (__bf16)(acc[e] * inv);
        ob[e] = (__bf16)(acc[8 + e] * inv);
    }
    size_t off = ((size_t)(b * SEQ) + qp * 32 + row) * DIM + h * HD + dseg;
    *(bf16x8*)&ctx[off] = oa;
    *(bf16x8*)&ctx[off + 8] = ob;
}

extern "C" void kernel_launch(void* const* d_in, const int* in_sizes, int n_in,
                              void* d_out, int out_size, void* d_ws, size_t ws_size,
                              hipStream_t stream) {
    const float* x = (const float*)d_in[0];
    const float* w_norm = (const float*)d_in[1];
    const float* Wq = (const float*)d_in[2];
    const float* Wk = (const float*)d_in[3];
    const float* Wv = (const float*)d_in[4];
    const float* Wo = (const float*)d_in[5];
    float* out = (float*)d_out;
    char* w8 = (char*)d_ws;

    const size_t MB = 1ull << 20;
    // [0,8): xn; [8,14): wtq/wtk/wtv — dead after QKV GEMM, reused for partials.
    __bf16* xn = (__bf16*)(w8);
    __bf16* wtq = (__bf16*)(w8 + 8 * MB);
    __bf16* wtk = (__bf16*)(w8 + 10 * MB);
    __bf16* wtv = (__bf16*)(w8 + 12 * MB);
    __bf16* part_O = (__bf16*)(w8);            // 3072 slots * 4KB = 12 MB [0,12)
    float* part_ml = (float*)(w8 + 12 * MB);   // 768 KB [12,12.75)
    __bf16* wto = (__bf16*)(w8 + 14 * MB);     // [14,16)
    __bf16* qf = (__bf16*)(w8 + 16 * MB);      // [16,24) fragment-major Q
    __bf16* kf = (__bf16*)(w8 + 24 * MB);      // [24,32) fragment-major K
    __bf16* vf = (__bf16*)(w8 + 32 * MB);      // [32,40) fragment-major V^T
    __bf16* ctx = (__bf16*)(w8 + 40 * MB);     // [40,48) row-major context
    float* cosT = (float*)(w8 + 48 * MB);      // 256 KB
    float* sinT = cosT + SEQ * 32;             // 256 KB

    wcvt_kernel<<<dim3(32, 32, 4), 256, 0, stream>>>(Wq, Wk, Wv, Wo, wtq, wtk, wtv, wto);
    rmsnorm_bf16<<<ROWS, 256, 0, stream>>>(x, w_norm, xn);
    rope_table_kernel<<<(SEQ * 32) / 256, 256, 0, stream>>>(cosT, sinT);

    gemm_qkv_kernel<<<768, 256, 0, stream>>>(xn, wtq, wtk, wtv, qf, kf, vf, cosT, sinT);

    attn_mfma_kernel<<<dim3(BATCH * NHEADS, 24), 256, 0, stream>>>(qf, kf, vf, part_O, part_ml);
    attn_combine_kernel<<<dim3(BATCH * NHEADS, SEQ / 32), 128, 0, stream>>>(part_O, part_ml, ctx);

    gemm_out_kernel<<<dim3(DIM / 128, ROWS / 128), 256, 0, stream>>>(ctx, wto, out);
}

// Round 13
// 139.033 us; speedup vs baseline: 1.0134x; 1.0134x over previous
//
#include <hip/hip_runtime.h>

#define DIM 1024
#define SEQ 2048
#define BATCH 2
#define NHEADS 16
#define HD 64
#define ROWS (BATCH * SEQ) // 4096

typedef __bf16 bf16x8 __attribute__((ext_vector_type(8)));
typedef __bf16 bf16x4 __attribute__((ext_vector_type(4)));
typedef float f32x4 __attribute__((ext_vector_type(4)));
typedef float f32x16 __attribute__((ext_vector_type(16)));
typedef unsigned u32x4 __attribute__((ext_vector_type(4)));

__device__ __forceinline__ f32x4 f4zero() {
    f32x4 z = {0.f, 0.f, 0.f, 0.f};
    return z;
}

__device__ __forceinline__ unsigned cvtpk(float lo, float hi) {
    unsigned r;
    asm("v_cvt_pk_bf16_f32 %0, %1, %2" : "=v"(r) : "v"(lo), "v"(hi));
    return r;
}

__device__ __forceinline__ void pl32swap(unsigned& a, unsigned& b) {
    asm volatile("v_permlane32_swap_b32 %0, %1" : "+v"(a), "+v"(b));
}

__device__ __forceinline__ float fexp2(float x) {
    float r;
    asm("v_exp_f32 %0, %1" : "=v"(r) : "v"(x));
    return r;
}

#define GLOAD_LDS16(g, l)                                                                  \
    __builtin_amdgcn_global_load_lds((const __attribute__((address_space(1))) void*)(g),   \
                                     (__attribute__((address_space(3))) void*)(l), 16, 0, 0)

// ---------------- RMSNorm -> bf16 ----------------
__global__ __launch_bounds__(256) void rmsnorm_bf16(const float* __restrict__ x,
                                                    const float* __restrict__ w,
                                                    __bf16* __restrict__ xn) {
    int row = blockIdx.x;
    int t = threadIdx.x;
    float4 v = ((const float4*)(x + (size_t)row * DIM))[t];
    float ss = v.x * v.x + v.y * v.y + v.z * v.z + v.w * v.w;
#pragma unroll
    for (int off = 1; off < 64; off <<= 1) ss += __shfl_xor(ss, off);
    __shared__ float red[4];
    if ((t & 63) == 0) red[t >> 6] = ss;
    __syncthreads();
    ss = red[0] + red[1] + red[2] + red[3];
    float scale = rsqrtf(ss * (1.0f / DIM) + 1e-5f);
    float4 wv = ((const float4*)w)[t];
    bf16x4 o;
    o[0] = (__bf16)(v.x * scale * wv.x);
    o[1] = (__bf16)(v.y * scale * wv.y);
    o[2] = (__bf16)(v.z * scale * wv.z);
    o[3] = (__bf16)(v.w * scale * wv.w);
    *(bf16x4*)(xn + (size_t)row * DIM + t * 4) = o;
}

// ---------------- Weight convert + transpose: W[k][n] f32 -> Wt[n][k] bf16 ----------------
__global__ __launch_bounds__(256) void wcvt_kernel(const float* __restrict__ Wq,
                                                   const float* __restrict__ Wk,
                                                   const float* __restrict__ Wv,
                                                   const float* __restrict__ Wo,
                                                   __bf16* tq, __bf16* tk, __bf16* tv, __bf16* to_) {
    int z = blockIdx.z;
    const float* W = z == 0 ? Wq : z == 1 ? Wk : z == 2 ? Wv : Wo;
    __bf16* T = z == 0 ? tq : z == 1 ? tk : z == 2 ? tv : to_;
    __shared__ float tile[32][33];
    int n0 = blockIdx.x * 32, k0 = blockIdx.y * 32;
    int tx = threadIdx.x & 31, ty = threadIdx.x >> 5;
#pragma unroll
    for (int j = 0; j < 32; j += 8) tile[ty + j][tx] = W[(size_t)(k0 + ty + j) * DIM + n0 + tx];
    __syncthreads();
#pragma unroll
    for (int j = 0; j < 32; j += 8)
        T[(size_t)(n0 + ty + j) * DIM + k0 + tx] = (__bf16)tile[tx][ty + j];
}

// ---------------- RoPE table ----------------
__global__ __launch_bounds__(256) void rope_table_kernel(float* __restrict__ cosT,
                                                         float* __restrict__ sinT) {
    int idx = blockIdx.x * 256 + threadIdx.x; // SEQ*32
    int s = idx >> 5, i = idx & 31;
    float e = (2.0f * (float)i) / 64.0f;
    float theta = 1.0f / powf(1000000.0f, e);
    float ang = (float)s * theta;
    cosT[idx] = cosf(ang);
    sinT[idx] = sinf(ang);
}

// ---------------- MFMA GEMM core (m97-style), acc left in registers ----------------
__device__ __forceinline__ void gemm_core(const __bf16* __restrict__ A,
                                          const __bf16* __restrict__ Bt,
                                          int K, __bf16* As, __bf16* Bs,
                                          f32x4 (&acc)[4][4], int row0, int col0) {
    int tid = threadIdx.x;
    int w = tid >> 6, l = tid & 63, l15 = l & 15, g = l >> 4;
    int wr = (w >> 1) << 6, wc = (w & 1) << 6;

    int sr0 = tid >> 2;
    int sr1 = 64 + (tid >> 2);
    int lc0 = (((tid & 3) ^ ((tid >> 3) & 3)) << 3); // swizzled source chunk
    const __bf16* gA0 = A + (size_t)(row0 + sr0) * K + lc0;
    const __bf16* gA1 = A + (size_t)(row0 + sr1) * K + lc0;
    const __bf16* gB0 = Bt + (size_t)(col0 + sr0) * K + lc0;
    const __bf16* gB1 = Bt + (size_t)(col0 + sr1) * K + lc0;
    __bf16* lA0 = As + w * 512;
    __bf16* lA1 = As + 2048 + w * 512;
    __bf16* lB0 = Bs + w * 512;
    __bf16* lB1 = Bs + 2048 + w * 512;

    int rca = ((g ^ ((l15 >> 1) & 3)) << 3); // swizzled read chunk

#pragma unroll
    for (int i = 0; i < 4; ++i)
#pragma unroll
        for (int j = 0; j < 4; ++j) acc[i][j] = f4zero();

    for (int k0 = 0; k0 < K; k0 += 32) {
        __syncthreads();
        GLOAD_LDS16(gA0 + k0, lA0);
        GLOAD_LDS16(gA1 + k0, lA1);
        GLOAD_LDS16(gB0 + k0, lB0);
        GLOAD_LDS16(gB1 + k0, lB1);
        __syncthreads();

        bf16x8 af[4], bfr[4];
#pragma unroll
        for (int i = 0; i < 4; ++i) af[i] = *(const bf16x8*)&As[(wr + i * 16 + l15) * 32 + rca];
#pragma unroll
        for (int j = 0; j < 4; ++j) bfr[j] = *(const bf16x8*)&Bs[(wc + j * 16 + l15) * 32 + rca];
        __builtin_amdgcn_s_setprio(1);
#pragma unroll
        for (int i = 0; i < 4; ++i)
#pragma unroll
            for (int j = 0; j < 4; ++j)
                acc[i][j] = __builtin_amdgcn_mfma_f32_16x16x32_bf16(af[i], bfr[j], acc[i][j], 0, 0, 0);
        __builtin_amdgcn_s_setprio(0);
    }
}

// Fused QKV GEMM, 768 blocks. Outputs written in MFMA FRAGMENT ORDER via an
// LDS-staged epilogue (wave-private 64x36 region, coalesced 1KB fragment stores):
//  Q/K: f[bh][s32][g][lane][e], lane=(s&31)|hi<<5, dd=g*16+hi*8+e (RoPE fused).
//  V:   vf[bh][t32][half][kk][lane][e], lane=(d&31)|((s>>3)&1)<<5.
__global__ __launch_bounds__(256) void gemm_qkv_kernel(const __bf16* __restrict__ xn,
                                                       const __bf16* __restrict__ wq,
                                                       const __bf16* __restrict__ wk,
                                                       const __bf16* __restrict__ wv,
                                                       __bf16* __restrict__ qf,
                                                       __bf16* __restrict__ kf,
                                                       __bf16* __restrict__ vf,
                                                       const float* __restrict__ cosT,
                                                       const float* __restrict__ sinT) {
    __shared__ __bf16 smem[9216]; // gemm: As=smem[0..4096), Bs=smem[4096..8192); epilogue: 4x 64x36
    __bf16* As = smem;
    __bf16* Bs = smem + 4096;
    int bid = blockIdx.x;
    int tid = threadIdx.x;
    int w = tid >> 6, l = tid & 63, l15 = l & 15, gq = l >> 4;
    int l31 = l & 31, hi = l >> 5;
    int wr = (w >> 1) << 6, wc = (w & 1) << 6;
    __bf16* Ls = smem + w * 2304; // wave-private 64x36
    f32x4 acc[4][4];

    if (bid < 512) {
        int z = bid >> 8, t = bid & 255;
        int col0 = (t & 7) << 7, row0 = (t >> 3) << 7;
        gemm_core(xn, z ? wk : wq, DIM, As, Bs, acc, row0, col0);
        __syncthreads(); // all waves done reading As/Bs before epilogue reuse
        __bf16* F = z ? kf : qf;
        int colbase = col0 + wc;
        int hh = colbase >> 6;                 // head (quadrant = one head)
        int row0w = row0 + wr;                 // first token of quadrant
        int bb = row0w >> 11;
        int bh = bb * 16 + hh;
        int tbase = (row0w & (SEQ - 1)) >> 5;  // first s32 tile
#pragma unroll
        for (int p = 0; p < 2; ++p) {
            // stage quadrant half (cols dd in [p*32, p*32+32)) with RoPE applied
#pragma unroll
            for (int i = 0; i < 4; ++i) {
#pragma unroll
                for (int r = 0; r < 4; ++r) {
                    int row64 = i * 16 + gq * 4 + r;
                    int s = (row0w + row64) & (SEQ - 1);
#pragma unroll
                    for (int jj = 0; jj < 2; ++jj) {
                        float c = cosT[s * 32 + jj * 16 + l15];
                        float sn = sinT[s * 32 + jj * 16 + l15];
                        float val;
                        if (p == 0)
                            val = acc[i][jj][r] * c - acc[i][jj + 2][r] * sn;
                        else
                            val = acc[i][jj][r] * sn + acc[i][jj + 2][r] * c;
                        Ls[row64 * 36 + jj * 16 + l15] = (__bf16)val;
                    }
                }
            }
            // read in fragment order, coalesced 16B/lane stores (in-wave DS ordering)
#pragma unroll
            for (int si = 0; si < 2; ++si) {
#pragma unroll
                for (int gg = 0; gg < 2; ++gg) {
                    int g = 2 * p + gg;
                    bf16x8 v = *(const bf16x8*)&Ls[(si * 32 + l31) * 36 + gg * 16 + hi * 8];
                    size_t dst = (((size_t)(bh * 64 + tbase + si) * 4 + g) * 64 + l) * 8;
                    *(bf16x8*)&F[dst] = v;
                }
            }
        }
    } else {
        int t = bid - 512;           // 256 blocks: [batch 2][n-blocks 8][s-blocks 16]
        int b = t >> 7, r7 = t & 127;
        int row0 = (r7 >> 4) << 7;   // n
        int col0 = (r7 & 15) << 7;   // s
        gemm_core(wv, xn + (size_t)b * SEQ * DIM, DIM, As, Bs, acc, row0, col0);
        __syncthreads();
        int hh = (row0 + wr) >> 6;   // head (n quadrant = one head)
        int bh = b * 16 + hh;
#pragma unroll
        for (int p = 0; p < 2; ++p) {
            // stage quadrant half (s cols in [p*32, p*32+32))
#pragma unroll
            for (int i = 0; i < 4; ++i) {
#pragma unroll
                for (int r = 0; r < 4; ++r) {
                    int row64 = i * 16 + gq * 4 + r;
#pragma unroll
                    for (int jj = 0; jj < 2; ++jj)
                        Ls[row64 * 36 + jj * 16 + l15] = (__bf16)acc[i][2 * p + jj][r];
                }
            }
            int t32 = ((col0 + wc) >> 5) + p;
#pragma unroll
            for (int half = 0; half < 2; ++half) {
#pragma unroll
                for (int kk = 0; kk < 2; ++kk) {
                    bf16x8 v = *(const bf16x8*)&Ls[(half * 32 + l31) * 36 + kk * 16 + hi * 8];
                    size_t dst = ((((size_t)(bh * 64 + t32) * 2 + half) * 2 + kk) * 64 + l) * 8;
                    *(bf16x8*)&vf[dst] = v;
                }
            }
        }
    }
}

__global__ __launch_bounds__(256) void gemm_out_kernel(const __bf16* __restrict__ ctx,
                                                       const __bf16* __restrict__ wo,
                                                       float* __restrict__ out) {
    __shared__ __bf16 As[128 * 32];
    __shared__ __bf16 Bs[128 * 32];
    int row0 = (int)blockIdx.y << 7, col0 = (int)blockIdx.x << 7;
    f32x4 acc[4][4];
    gemm_core(ctx, wo, DIM, As, Bs, acc, row0, col0);
    int tid = threadIdx.x;
    int w = tid >> 6, l = tid & 63, l15 = l & 15, g = l >> 4;
    int wr = (w >> 1) << 6, wc = (w & 1) << 6;
#pragma unroll
    for (int i = 0; i < 4; ++i)
#pragma unroll
        for (int j = 0; j < 4; ++j)
#pragma unroll
            for (int r = 0; r < 4; ++r) {
                int row = row0 + wr + i * 16 + g * 4 + r;
                int col = col0 + wc + j * 16 + l15;
                out[(size_t)row * DIM + col] = acc[i][j][r];
            }
}

// ---------------- Barrier-free split-KV attention on fragment-major buffers ----------------
// Grid (32 bh, 24) x 256 thr = 4 independent waves/block; 96 slots/bh (chunks of 1024 KV
// positions, <=2 per 32-row q-strip). All operand loads are coalesced 1KB fragment reads.
// No LDS, no barriers; ping-pong K prefetch; per-wave online softmax (verified r7 math).
__global__ __launch_bounds__(256, 3) void attn_mfma_kernel(const __bf16* __restrict__ qf,
                                                           const __bf16* __restrict__ kf,
                                                           const __bf16* __restrict__ vf,
                                                           __bf16* __restrict__ part_O,
                                                           float* __restrict__ part_ml) {
    int bh = blockIdx.x;
    int tid = threadIdx.x, wvx = tid >> 6, l = tid & 63;
    int wslot = (int)blockIdx.y * 4 + wvx;
    int slot = 95 - wslot; // heavy first
    int qp, ci;
    if (slot < 32) {
        qp = slot;
        ci = 0;
    } else {
        int t = slot - 32;
        qp = 32 + (t >> 1);
        ci = t & 1;
    }
    int rem = qp - (ci << 5);
    int ntiles = rem < 32 ? rem + 1 : 32;
    int dtile = rem < 32 ? rem : -1;
    int t0 = ci << 5;

    int l31 = l & 31, hi = l >> 5;
    int qrow = qp * 32 + l31;

    // Q fragments (coalesced), pre-scaled by 0.125*log2(e)
    bf16x8 qfr[4];
    {
        const __bf16* qp_ = qf + ((size_t)bh * 64 + qp) * 2048 + (size_t)l * 8;
        const float c2 = 0.125f * 1.44269504f;
#pragma unroll
        for (int g = 0; g < 4; ++g) {
            bf16x8 tq = *(const bf16x8*)(qp_ + g * 512);
#pragma unroll
            for (int e = 0; e < 8; ++e) qfr[g][e] = (__bf16)((float)tq[e] * c2);
        }
    }

    const __bf16* kfp = kf + ((size_t)bh * 64 + t0) * 2048 + (size_t)l * 8;
    const __bf16* vfp = vf + ((size_t)bh * 64 + t0) * 2048 + (size_t)l * 8;

    f32x16 oA, oB;
#pragma unroll
    for (int r = 0; r < 16; ++r) {
        oA[r] = 0.f;
        oB[r] = 0.f;
    }
    float m_run = -1e30f, l_run = 0.f;

    bf16x8 ka[4], kb[4];
#pragma unroll
    for (int g = 0; g < 4; ++g) ka[g] = *(const bf16x8*)(kfp + g * 512);

    auto tile_body = [&](bf16x8 (&kcur)[4], bf16x8 (&knxt)[4], int st) {
        if (st + 1 < ntiles) { // prefetch next K tile (coalesced)
            const __bf16* kn = kfp + (size_t)(st + 1) * 2048;
#pragma unroll
            for (int g = 0; g < 4; ++g) knxt[g] = *(const bf16x8*)(kn + g * 512);
        }
        const __bf16* vp = vfp + (size_t)st * 2048; // V frags, consumed after softmax
        bf16x8 v00 = *(const bf16x8*)(vp);
        bf16x8 v01 = *(const bf16x8*)(vp + 512);
        bf16x8 v10 = *(const bf16x8*)(vp + 1024);
        bf16x8 v11 = *(const bf16x8*)(vp + 1536);

        // S^T = mfma(K, Q): rows = 32 k-pos of this tile, cols = q (lane&31)
        f32x16 sa;
#pragma unroll
        for (int r = 0; r < 16; ++r) sa[r] = 0.f;
        __builtin_amdgcn_s_setprio(1);
#pragma unroll
        for (int g = 0; g < 4; ++g)
            sa = __builtin_amdgcn_mfma_f32_32x32x16_bf16(kcur[g], qfr[g], sa, 0, 0, 0);
        __builtin_amdgcn_s_setprio(0);

        if (st == dtile) { // causal mask on the diagonal tile
            int s0 = (t0 + st) << 5;
#pragma unroll
            for (int r = 0; r < 16; ++r) {
                int kg = s0 + (r & 3) + 8 * (r >> 2) + 4 * hi;
                if (kg > qrow) sa[r] = -1e30f;
            }
        }

        // online softmax (exp2 domain), defer-max THR=10; native v_exp_f32
        float mx[8];
#pragma unroll
        for (int r = 0; r < 8; ++r) mx[r] = fmaxf(sa[r], sa[r + 8]);
#pragma unroll
        for (int r = 0; r < 4; ++r) mx[r] = fmaxf(mx[r], mx[r + 4]);
        float lmax = fmaxf(fmaxf(mx[0], mx[1]), fmaxf(mx[2], mx[3]));
        if (!__all(lmax <= m_run + 10.0f)) {
            float omax = fmaxf(lmax, __shfl_xor(lmax, 32));
            float m_new = fmaxf(m_run, omax);
            float alpha = fexp2(m_run - m_new);
            l_run *= alpha;
#pragma unroll
            for (int r = 0; r < 16; ++r) {
                oA[r] *= alpha;
                oB[r] *= alpha;
            }
            m_run = m_new;
        }
#pragma unroll
        for (int r = 0; r < 16; ++r) sa[r] = fexp2(sa[r] - m_run);
        float s8[8];
#pragma unroll
        for (int r = 0; r < 8; ++r) s8[r] = sa[r] + sa[r + 8];
#pragma unroll
        for (int r = 0; r < 4; ++r) s8[r] += s8[r + 4];
        float ls = (s8[0] + s8[1]) + (s8[2] + s8[3]);
        l_run += ls + __shfl_xor(ls, 32);

        // pack P -> bf16 B-frags pa0 (k 0..15), pa1 (k 16..31)
        unsigned a0 = cvtpk(sa[0], sa[1]), b0 = cvtpk(sa[4], sa[5]);
        pl32swap(a0, b0);
        unsigned c0 = cvtpk(sa[2], sa[3]), d0 = cvtpk(sa[6], sa[7]);
        pl32swap(c0, d0);
        u32x4 t4a = {a0, c0, b0, d0};
        bf16x8 pa0 = __builtin_bit_cast(bf16x8, t4a);
        unsigned a1 = cvtpk(sa[8], sa[9]), b1 = cvtpk(sa[12], sa[13]);
        pl32swap(a1, b1);
        unsigned c1 = cvtpk(sa[10], sa[11]), d1 = cvtpk(sa[14], sa[15]);
        pl32swap(c1, d1);
        u32x4 t4b = {a1, c1, b1, d1};
        bf16x8 pa1 = __builtin_bit_cast(bf16x8, t4b);

        // O^T += mfma(V^T, P)
        __builtin_amdgcn_s_setprio(1);
        oA = __builtin_amdgcn_mfma_f32_32x32x16_bf16(v00, pa0, oA, 0, 0, 0);
        oA = __builtin_amdgcn_mfma_f32_32x32x16_bf16(v01, pa1, oA, 0, 0, 0);
        oB = __builtin_amdgcn_mfma_f32_32x32x16_bf16(v10, pa0, oB, 0, 0, 0);
        oB = __builtin_amdgcn_mfma_f32_32x32x16_bf16(v11, pa1, oB, 0, 0, 0);
        __builtin_amdgcn_s_setprio(0);
    };

    int st = 0;
    while (st < ntiles) {
        tile_body(ka, kb, st);
        ++st;
        if (st >= ntiles) break;
        tile_body(kb, ka, st);
        ++st;
    }

    // write unnormalized partial: O bf16 [slot][32 q][64 d], m/l f32 [slot][2][32]
    int gslot = bh * 96 + slot;
    __bf16* po = part_O + (size_t)gslot * 2048 + l31 * 64;
#pragma unroll
    for (int rr = 0; rr < 16; rr += 4) {
        int d0 = 8 * (rr >> 2) + 4 * hi;
        uint2 pA = {cvtpk(oA[rr], oA[rr + 1]), cvtpk(oA[rr + 2], oA[rr + 3])};
        uint2 pB = {cvtpk(oB[rr], oB[rr + 1]), cvtpk(oB[rr + 2], oB[rr + 3])};
        *(uint2*)&po[d0] = pA;
        *(uint2*)&po[32 + d0] = pB;
    }
    if (hi == 0) {
        part_ml[(size_t)gslot * 64 + l31] = m_run;
        part_ml[(size_t)gslot * 64 + 32 + l31] = l_run;
    }
}

// ---------------- Combine split-KV partials -> ctx (row-major) ----------------
__global__ __launch_bounds__(128) void attn_combine_kernel(const __bf16* __restrict__ part_O,
                                                           const float* __restrict__ part_ml,
                                                           __bf16* __restrict__ ctx) {
    int bh = blockIdx.x, qp = blockIdx.y;
    int b = bh >> 4, h = bh & 15;
    int nch = 1 + (qp >> 5);
    int base = qp < 32 ? qp : 32 + 2 * (qp - 32);
    size_t so = (size_t)bh * 96 + base;
    int t = threadIdx.x;
    int row = t >> 2, dseg = (t & 3) << 4;

    float mv0 = part_ml[so * 64 + row];
    float mv1 = -1e30f;
    if (nch > 1) mv1 = part_ml[(so + 1) * 64 + row];
    float mmax = fmaxf(mv0, mv1);

    float acc[16];
#pragma unroll
    for (int e = 0; e < 16; ++e) acc[e] = 0.f;
    float lsum = 0.f;

#pragma unroll 2
    for (int i = 0; i < 2; ++i) {
        if (i >= nch) break;
        float mi = i == 0 ? mv0 : mv1;
        float wsc = fexp2(mi - mmax);
        lsum += wsc * part_ml[(so + i) * 64 + 32 + row];
        const __bf16* po = part_O + (so + i) * 2048 + row * 64 + dseg;
        bf16x8 a = *(const bf16x8*)po;
        bf16x8 b2 = *(const bf16x8*)(po + 8);
#pragma unroll
        for (int e = 0; e < 8; ++e) {
            acc[e] += wsc * (float)a[e];
            acc[8 + e] += wsc * (float)b2[e];
        }
    }

    float inv = 1.0f / lsum;
    bf16x8 oa, ob;
#pragma unroll
    for (int e = 0; e < 8; ++e) {
        oa[e] = (__bf16)(acc[e] * inv);
        ob[e] = (__bf16)(acc[8 + e] * inv);
    }
    size_t off = ((size_t)(b * SEQ) + qp * 32 + row) * DIM + h * HD + dseg;
    *(bf16x8*)&ctx[off] = oa;
    *(bf16x8*)&ctx[off + 8] = ob;
}

extern "C" void kernel_launch(void* const* d_in, const int* in_sizes, int n_in,
                              void* d_out, int out_size, void* d_ws, size_t ws_size,
                              hipStream_t stream) {
    const float* x = (const float*)d_in[0];
    const float* w_norm = (const float*)d_in[1];
    const float* Wq = (const float*)d_in[2];
    const float* Wk = (const float*)d_in[3];
    const float* Wv = (const float*)d_in[4];
    const float* Wo = (const float*)d_in[5];
    float* out = (float*)d_out;
    char* w8 = (char*)d_ws;

    const size_t MB = 1ull << 20;
    // [0,8): xn; [8,14): wtq/wtk/wtv — dead after QKV GEMM, reused for partials.
    __bf16* xn = (__bf16*)(w8);
    __bf16* wtq = (__bf16*)(w8 + 8 * MB);
    __bf16* wtk = (__bf16*)(w8 + 10 * MB);
    __bf16* wtv = (__bf16*)(w8 + 12 * MB);
    __bf16* part_O = (__bf16*)(w8);            // 3072 slots * 4KB = 12 MB [0,12)
    float* part_ml = (float*)(w8 + 12 * MB);   // 768 KB [12,12.75)
    __bf16* wto = (__bf16*)(w8 + 14 * MB);     // [14,16)
    __bf16* qf = (__bf16*)(w8 + 16 * MB);      // [16,24) fragment-major Q
    __bf16* kf = (__bf16*)(w8 + 24 * MB);      // [24,32) fragment-major K
    __bf16* vf = (__bf16*)(w8 + 32 * MB);      // [32,40) fragment-major V^T
    __bf16* ctx = (__bf16*)(w8 + 40 * MB);     // [40,48) row-major context
    float* cosT = (float*)(w8 + 48 * MB);      // 256 KB
    float* sinT = cosT + SEQ * 32;             // 256 KB

    wcvt_kernel<<<dim3(32, 32, 4), 256, 0, stream>>>(Wq, Wk, Wv, Wo, wtq, wtk, wtv, wto);
    rmsnorm_bf16<<<ROWS, 256, 0, stream>>>(x, w_norm, xn);
    rope_table_kernel<<<(SEQ * 32) / 256, 256, 0, stream>>>(cosT, sinT);

    gemm_qkv_kernel<<<768, 256, 0, stream>>>(xn, wtq, wtk, wtv, qf, kf, vf, cosT, sinT);

    attn_mfma_kernel<<<dim3(BATCH * NHEADS, 24), 256, 0, stream>>>(qf, kf, vf, part_O, part_ml);
    attn_combine_kernel<<<dim3(BATCH * NHEADS, SEQ / 32), 128, 0, stream>>>(part_O, part_ml, ctx);

    gemm_out_kernel<<<dim3(DIM / 128, ROWS / 128), 256, 0, stream>>>(ctx, wto, out);
}

// Round 14
// 134.346 us; speedup vs baseline: 1.0487x; 1.0349x over previous
//
#include <hip/hip_runtime.h>

#define DIM 1024
#define SEQ 2048
#define BATCH 2
#define NHEADS 16
#define HD 64
#define ROWS (BATCH * SEQ) // 4096

typedef __bf16 bf16x8 __attribute__((ext_vector_type(8)));
typedef __bf16 bf16x4 __attribute__((ext_vector_type(4)));
typedef float f32x4 __attribute__((ext_vector_type(4)));
typedef float f32x16 __attribute__((ext_vector_type(16)));
typedef unsigned u32x4 __attribute__((ext_vector_type(4)));

__device__ __forceinline__ f32x4 f4zero() {
    f32x4 z = {0.f, 0.f, 0.f, 0.f};
    return z;
}

__device__ __forceinline__ unsigned cvtpk(float lo, float hi) {
    unsigned r;
    asm("v_cvt_pk_bf16_f32 %0, %1, %2" : "=v"(r) : "v"(lo), "v"(hi));
    return r;
}

__device__ __forceinline__ void pl32swap(unsigned& a, unsigned& b) {
    asm volatile("v_permlane32_swap_b32 %0, %1" : "+v"(a), "+v"(b));
}

__device__ __forceinline__ float fexp2(float x) {
    float r;
    asm("v_exp_f32 %0, %1" : "=v"(r) : "v"(x));
    return r;
}

#define GLOAD_LDS16(g, l)                                                                  \
    __builtin_amdgcn_global_load_lds((const __attribute__((address_space(1))) void*)(g),   \
                                     (__attribute__((address_space(3))) void*)(l), 16, 0, 0)

// ---------------- RMSNorm -> bf16 ----------------
__global__ __launch_bounds__(256) void rmsnorm_bf16(const float* __restrict__ x,
                                                    const float* __restrict__ w,
                                                    __bf16* __restrict__ xn) {
    int row = blockIdx.x;
    int t = threadIdx.x;
    float4 v = ((const float4*)(x + (size_t)row * DIM))[t];
    float ss = v.x * v.x + v.y * v.y + v.z * v.z + v.w * v.w;
#pragma unroll
    for (int off = 1; off < 64; off <<= 1) ss += __shfl_xor(ss, off);
    __shared__ float red[4];
    if ((t & 63) == 0) red[t >> 6] = ss;
    __syncthreads();
    ss = red[0] + red[1] + red[2] + red[3];
    float scale = rsqrtf(ss * (1.0f / DIM) + 1e-5f);
    float4 wv = ((const float4*)w)[t];
    bf16x4 o;
    o[0] = (__bf16)(v.x * scale * wv.x);
    o[1] = (__bf16)(v.y * scale * wv.y);
    o[2] = (__bf16)(v.z * scale * wv.z);
    o[3] = (__bf16)(v.w * scale * wv.w);
    *(bf16x4*)(xn + (size_t)row * DIM + t * 4) = o;
}

// ---------------- Weight convert + transpose: W[k][n] f32 -> Wt[n][k] bf16 ----------------
__global__ __launch_bounds__(256) void wcvt_kernel(const float* __restrict__ Wq,
                                                   const float* __restrict__ Wk,
                                                   const float* __restrict__ Wv,
                                                   const float* __restrict__ Wo,
                                                   __bf16* tq, __bf16* tk, __bf16* tv, __bf16* to_) {
    int z = blockIdx.z;
    const float* W = z == 0 ? Wq : z == 1 ? Wk : z == 2 ? Wv : Wo;
    __bf16* T = z == 0 ? tq : z == 1 ? tk : z == 2 ? tv : to_;
    __shared__ float tile[32][33];
    int n0 = blockIdx.x * 32, k0 = blockIdx.y * 32;
    int tx = threadIdx.x & 31, ty = threadIdx.x >> 5;
#pragma unroll
    for (int j = 0; j < 32; j += 8) tile[ty + j][tx] = W[(size_t)(k0 + ty + j) * DIM + n0 + tx];
    __syncthreads();
#pragma unroll
    for (int j = 0; j < 32; j += 8)
        T[(size_t)(n0 + ty + j) * DIM + k0 + tx] = (__bf16)tile[tx][ty + j];
}

// ---------------- RoPE table ----------------
__global__ __launch_bounds__(256) void rope_table_kernel(float* __restrict__ cosT,
                                                         float* __restrict__ sinT) {
    int idx = blockIdx.x * 256 + threadIdx.x; // SEQ*32
    int s = idx >> 5, i = idx & 31;
    float e = (2.0f * (float)i) / 64.0f;
    float theta = 1.0f / powf(1000000.0f, e);
    float ang = (float)s * theta;
    cosT[idx] = cosf(ang);
    sinT[idx] = sinf(ang);
}

// ---------------- MFMA GEMM core, BK=64 (16 barrier-pairs for K=1024) ----------------
// LDS [128][64] per operand, 8-chunk rows with XOR swizzle (chunk ^= row&7) applied on
// global source AND ds_read address (G21); gload_lds dest stays linear.
__device__ __forceinline__ void gemm_core64(const __bf16* __restrict__ A,
                                            const __bf16* __restrict__ Bt,
                                            int K, __bf16* As, __bf16* Bs,
                                            f32x4 (&acc)[4][4], int row0, int col0) {
    int tid = threadIdx.x;
    int w = tid >> 6, l = tid & 63, l15 = l & 15, g = l >> 4;
    int wr = (w >> 1) << 6, wc = (w & 1) << 6;

    int srow = tid >> 3;                          // 0..31 (row within 32-row call)
    int schunk = ((tid & 7) ^ (srow & 7)) << 3;   // swizzled source col (elems)
    const __bf16* gA = A + (size_t)(row0 + srow) * K + schunk;
    const __bf16* gB = Bt + (size_t)(col0 + srow) * K + schunk;
    __bf16* lA = As + w * 512; // + c*2048 per call
    __bf16* lB = Bs + w * 512;

#pragma unroll
    for (int i = 0; i < 4; ++i)
#pragma unroll
        for (int j = 0; j < 4; ++j) acc[i][j] = f4zero();

    int xr = (l15 & 7);
    for (int k0 = 0; k0 < K; k0 += 64) {
        __syncthreads();
#pragma unroll
        for (int c = 0; c < 4; ++c) {
            GLOAD_LDS16(gA + (size_t)(c * 32) * K + k0, lA + c * 2048);
            GLOAD_LDS16(gB + (size_t)(c * 32) * K + k0, lB + c * 2048);
        }
        __syncthreads();
#pragma unroll
        for (int kk = 0; kk < 2; ++kk) {
            int q8 = kk * 4 + g;
            int rc = (q8 ^ xr) << 3;
            bf16x8 af[4], bfr[4];
#pragma unroll
            for (int i = 0; i < 4; ++i)
                af[i] = *(const bf16x8*)&As[(wr + i * 16 + l15) * 64 + rc];
#pragma unroll
            for (int j = 0; j < 4; ++j)
                bfr[j] = *(const bf16x8*)&Bs[(wc + j * 16 + l15) * 64 + rc];
            __builtin_amdgcn_s_setprio(1);
#pragma unroll
            for (int i = 0; i < 4; ++i)
#pragma unroll
                for (int j = 0; j < 4; ++j)
                    acc[i][j] = __builtin_amdgcn_mfma_f32_16x16x32_bf16(af[i], bfr[j], acc[i][j], 0, 0, 0);
            __builtin_amdgcn_s_setprio(0);
        }
    }
}

// Fused QKV GEMM, 768 blocks (XCD-swizzled). Outputs in MFMA FRAGMENT ORDER via the
// LDS-staged epilogue (wave-private 64x36), nontemporal 16B fragment stores:
//  Q/K: f[bh][s32][g][lane][e], lane=(s&31)|hi<<5, dd=g*16+hi*8+e (RoPE fused).
//  V:   vf[bh][t32][half][kk][lane][e], lane=(d&31)|((s>>3)&1)<<5.
__global__ __launch_bounds__(256) void gemm_qkv_kernel(const __bf16* __restrict__ xn,
                                                       const __bf16* __restrict__ wq,
                                                       const __bf16* __restrict__ wk,
                                                       const __bf16* __restrict__ wv,
                                                       __bf16* __restrict__ qf,
                                                       __bf16* __restrict__ kf,
                                                       __bf16* __restrict__ vf,
                                                       const float* __restrict__ cosT,
                                                       const float* __restrict__ sinT) {
    __shared__ __bf16 smem[16384]; // gemm: As[8192] + Bs[8192]; epilogue reuses As region
    __bf16* As = smem;
    __bf16* Bs = smem + 8192;
    int bid0 = blockIdx.x;
    int bid = ((bid0 & 7) * 96) + (bid0 >> 3); // XCD-bijective swizzle (768 = 8*96)
    int tid = threadIdx.x;
    int w = tid >> 6, l = tid & 63, l15 = l & 15, gq = l >> 4;
    int l31 = l & 31, hi = l >> 5;
    int wr = (w >> 1) << 6, wc = (w & 1) << 6;
    __bf16* Ls = smem + w * 2304; // wave-private 64x36
    f32x4 acc[4][4];

    if (bid < 512) {
        int z = bid >> 8, t = bid & 255;
        int col0 = (t & 7) << 7, row0 = (t >> 3) << 7;
        gemm_core64(xn, z ? wk : wq, DIM, As, Bs, acc, row0, col0);
        __syncthreads(); // all waves done reading As/Bs before epilogue reuse
        __bf16* F = z ? kf : qf;
        int colbase = col0 + wc;
        int hh = colbase >> 6;                 // head (quadrant = one head)
        int row0w = row0 + wr;                 // first token of quadrant
        int bb = row0w >> 11;
        int bh = bb * 16 + hh;
        int tbase = (row0w & (SEQ - 1)) >> 5;  // first s32 tile
#pragma unroll
        for (int p = 0; p < 2; ++p) {
            // stage quadrant half (cols dd in [p*32, p*32+32)) with RoPE applied
#pragma unroll
            for (int i = 0; i < 4; ++i) {
#pragma unroll
                for (int r = 0; r < 4; ++r) {
                    int row64 = i * 16 + gq * 4 + r;
                    int s = (row0w + row64) & (SEQ - 1);
#pragma unroll
                    for (int jj = 0; jj < 2; ++jj) {
                        float c = cosT[s * 32 + jj * 16 + l15];
                        float sn = sinT[s * 32 + jj * 16 + l15];
                        float val;
                        if (p == 0)
                            val = acc[i][jj][r] * c - acc[i][jj + 2][r] * sn;
                        else
                            val = acc[i][jj][r] * sn + acc[i][jj + 2][r] * c;
                        Ls[row64 * 36 + jj * 16 + l15] = (__bf16)val;
                    }
                }
            }
            // read in fragment order, coalesced nontemporal 16B/lane stores
#pragma unroll
            for (int si = 0; si < 2; ++si) {
#pragma unroll
                for (int gg = 0; gg < 2; ++gg) {
                    int g = 2 * p + gg;
                    bf16x8 v = *(const bf16x8*)&Ls[(si * 32 + l31) * 36 + gg * 16 + hi * 8];
                    size_t dst = (((size_t)(bh * 64 + tbase + si) * 4 + g) * 64 + l) * 8;
                    __builtin_nontemporal_store(v, (bf16x8*)&F[dst]);
                }
            }
        }
    } else {
        int t = bid - 512;           // 256 blocks: [batch 2][n-blocks 8][s-blocks 16]
        int b = t >> 7, r7 = t & 127;
        int row0 = (r7 >> 4) << 7;   // n
        int col0 = (r7 & 15) << 7;   // s
        gemm_core64(wv, xn + (size_t)b * SEQ * DIM, DIM, As, Bs, acc, row0, col0);
        __syncthreads();
        int hh = (row0 + wr) >> 6;   // head (n quadrant = one head)
        int bh = b * 16 + hh;
#pragma unroll
        for (int p = 0; p < 2; ++p) {
            // stage quadrant half (s cols in [p*32, p*32+32))
#pragma unroll
            for (int i = 0; i < 4; ++i) {
#pragma unroll
                for (int r = 0; r < 4; ++r) {
                    int row64 = i * 16 + gq * 4 + r;
#pragma unroll
                    for (int jj = 0; jj < 2; ++jj)
                        Ls[row64 * 36 + jj * 16 + l15] = (__bf16)acc[i][2 * p + jj][r];
                }
            }
            int t32 = ((col0 + wc) >> 5) + p;
#pragma unroll
            for (int half = 0; half < 2; ++half) {
#pragma unroll
                for (int kk = 0; kk < 2; ++kk) {
                    bf16x8 v = *(const bf16x8*)&Ls[(half * 32 + l31) * 36 + kk * 16 + hi * 8];
                    size_t dst = ((((size_t)(bh * 64 + t32) * 2 + half) * 2 + kk) * 64 + l) * 8;
                    __builtin_nontemporal_store(v, (bf16x8*)&vf[dst]);
                }
            }
        }
    }
}

__global__ __launch_bounds__(256) void gemm_out_kernel(const __bf16* __restrict__ ctx,
                                                       const __bf16* __restrict__ wo,
                                                       float* __restrict__ out) {
    __shared__ __bf16 As[8192];
    __shared__ __bf16 Bs[8192];
    int b0 = blockIdx.x;
    int t = ((b0 & 7) * 32) + (b0 >> 3); // XCD swizzle (256 = 8*32)
    int row0 = (t >> 3) << 7, col0 = (t & 7) << 7;
    f32x4 acc[4][4];
    gemm_core64(ctx, wo, DIM, As, Bs, acc, row0, col0);
    int tid = threadIdx.x;
    int w = tid >> 6, l = tid & 63, l15 = l & 15, g = l >> 4;
    int wr = (w >> 1) << 6, wc = (w & 1) << 6;
#pragma unroll
    for (int i = 0; i < 4; ++i)
#pragma unroll
        for (int j = 0; j < 4; ++j)
#pragma unroll
            for (int r = 0; r < 4; ++r) {
                int row = row0 + wr + i * 16 + g * 4 + r;
                int col = col0 + wc + j * 16 + l15;
                __builtin_nontemporal_store(acc[i][j][r], &out[(size_t)row * DIM + col]);
            }
}

// ---------------- Barrier-free split-KV attention on fragment-major buffers ----------------
// Grid (32 bh, 24) x 256 thr = 4 independent waves/block; 96 slots/bh (chunks of 1024 KV
// positions, <=2 per 32-row q-strip). All operand loads are coalesced 1KB fragment reads.
// No LDS, no barriers; ping-pong K prefetch; per-wave online softmax (verified r7 math).
__global__ __launch_bounds__(256, 3) void attn_mfma_kernel(const __bf16* __restrict__ qf,
                                                           const __bf16* __restrict__ kf,
                                                           const __bf16* __restrict__ vf,
                                                           __bf16* __restrict__ part_O,
                                                           float* __restrict__ part_ml) {
    int bh = blockIdx.x;
    int tid = threadIdx.x, wvx = tid >> 6, l = tid & 63;
    int wslot = (int)blockIdx.y * 4 + wvx;
    int slot = 95 - wslot; // heavy first
    int qp, ci;
    if (slot < 32) {
        qp = slot;
        ci = 0;
    } else {
        int t = slot - 32;
        qp = 32 + (t >> 1);
        ci = t & 1;
    }
    int rem = qp - (ci << 5);
    int ntiles = rem < 32 ? rem + 1 : 32;
    int dtile = rem < 32 ? rem : -1;
    int t0 = ci << 5;

    int l31 = l & 31, hi = l >> 5;
    int qrow = qp * 32 + l31;

    // Q fragments (coalesced), pre-scaled by 0.125*log2(e)
    bf16x8 qfr[4];
    {
        const __bf16* qp_ = qf + ((size_t)bh * 64 + qp) * 2048 + (size_t)l * 8;
        const float c2 = 0.125f * 1.44269504f;
#pragma unroll
        for (int g = 0; g < 4; ++g) {
            bf16x8 tq = *(const bf16x8*)(qp_ + g * 512);
#pragma unroll
            for (int e = 0; e < 8; ++e) qfr[g][e] = (__bf16)((float)tq[e] * c2);
        }
    }

    const __bf16* kfp = kf + ((size_t)bh * 64 + t0) * 2048 + (size_t)l * 8;
    const __bf16* vfp = vf + ((size_t)bh * 64 + t0) * 2048 + (size_t)l * 8;

    f32x16 oA, oB;
#pragma unroll
    for (int r = 0; r < 16; ++r) {
        oA[r] = 0.f;
        oB[r] = 0.f;
    }
    float m_run = -1e30f, l_run = 0.f;

    bf16x8 ka[4], kb[4];
#pragma unroll
    for (int g = 0; g < 4; ++g) ka[g] = *(const bf16x8*)(kfp + g * 512);

    auto tile_body = [&](bf16x8 (&kcur)[4], bf16x8 (&knxt)[4], int st) {
        if (st + 1 < ntiles) { // prefetch next K tile (coalesced)
            const __bf16* kn = kfp + (size_t)(st + 1) * 2048;
#pragma unroll
            for (int g = 0; g < 4; ++g) knxt[g] = *(const bf16x8*)(kn + g * 512);
        }
        const __bf16* vp = vfp + (size_t)st * 2048; // V frags, consumed after softmax
        bf16x8 v00 = *(const bf16x8*)(vp);
        bf16x8 v01 = *(const bf16x8*)(vp + 512);
        bf16x8 v10 = *(const bf16x8*)(vp + 1024);
        bf16x8 v11 = *(const bf16x8*)(vp + 1536);

        // S^T = mfma(K, Q): rows = 32 k-pos of this tile, cols = q (lane&31)
        f32x16 sa;
#pragma unroll
        for (int r = 0; r < 16; ++r) sa[r] = 0.f;
        __builtin_amdgcn_s_setprio(1);
#pragma unroll
        for (int g = 0; g < 4; ++g)
            sa = __builtin_amdgcn_mfma_f32_32x32x16_bf16(kcur[g], qfr[g], sa, 0, 0, 0);
        __builtin_amdgcn_s_setprio(0);

        if (st == dtile) { // causal mask on the diagonal tile
            int s0 = (t0 + st) << 5;
#pragma unroll
            for (int r = 0; r < 16; ++r) {
                int kg = s0 + (r & 3) + 8 * (r >> 2) + 4 * hi;
                if (kg > qrow) sa[r] = -1e30f;
            }
        }

        // online softmax (exp2 domain), defer-max THR=10; native v_exp_f32
        float mx[8];
#pragma unroll
        for (int r = 0; r < 8; ++r) mx[r] = fmaxf(sa[r], sa[r + 8]);
#pragma unroll
        for (int r = 0; r < 4; ++r) mx[r] = fmaxf(mx[r], mx[r + 4]);
        float lmax = fmaxf(fmaxf(mx[0], mx[1]), fmaxf(mx[2], mx[3]));
        if (!__all(lmax <= m_run + 10.0f)) {
            float omax = fmaxf(lmax, __shfl_xor(lmax, 32));
            float m_new = fmaxf(m_run, omax);
            float alpha = fexp2(m_run - m_new);
            l_run *= alpha;
#pragma unroll
            for (int r = 0; r < 16; ++r) {
                oA[r] *= alpha;
                oB[r] *= alpha;
            }
            m_run = m_new;
        }
#pragma unroll
        for (int r = 0; r < 16; ++r) sa[r] = fexp2(sa[r] - m_run);
        float s8[8];
#pragma unroll
        for (int r = 0; r < 8; ++r) s8[r] = sa[r] + sa[r + 8];
#pragma unroll
        for (int r = 0; r < 4; ++r) s8[r] += s8[r + 4];
        float ls = (s8[0] + s8[1]) + (s8[2] + s8[3]);
        l_run += ls + __shfl_xor(ls, 32);

        // pack P -> bf16 B-frags pa0 (k 0..15), pa1 (k 16..31)
        unsigned a0 = cvtpk(sa[0], sa[1]), b0 = cvtpk(sa[4], sa[5]);
        pl32swap(a0, b0);
        unsigned c0 = cvtpk(sa[2], sa[3]), d0 = cvtpk(sa[6], sa[7]);
        pl32swap(c0, d0);
        u32x4 t4a = {a0, c0, b0, d0};
        bf16x8 pa0 = __builtin_bit_cast(bf16x8, t4a);
        unsigned a1 = cvtpk(sa[8], sa[9]), b1 = cvtpk(sa[12], sa[13]);
        pl32swap(a1, b1);
        unsigned c1 = cvtpk(sa[10], sa[11]), d1 = cvtpk(sa[14], sa[15]);
        pl32swap(c1, d1);
        u32x4 t4b = {a1, c1, b1, d1};
        bf16x8 pa1 = __builtin_bit_cast(bf16x8, t4b);

        // O^T += mfma(V^T, P)
        __builtin_amdgcn_s_setprio(1);
        oA = __builtin_amdgcn_mfma_f32_32x32x16_bf16(v00, pa0, oA, 0, 0, 0);
        oA = __builtin_amdgcn_mfma_f32_32x32x16_bf16(v01, pa1, oA, 0, 0, 0);
        oB = __builtin_amdgcn_mfma_f32_32x32x16_bf16(v10, pa0, oB, 0, 0, 0);
        oB = __builtin_amdgcn_mfma_f32_32x32x16_bf16(v11, pa1, oB, 0, 0, 0);
        __builtin_amdgcn_s_setprio(0);
    };

    int st = 0;
    while (st < ntiles) {
        tile_body(ka, kb, st);
        ++st;
        if (st >= ntiles) break;
        tile_body(kb, ka, st);
        ++st;
    }

    // write unnormalized partial: O bf16 [slot][32 q][64 d], m/l f32 [slot][2][32]
    int gslot = bh * 96 + slot;
    __bf16* po = part_O + (size_t)gslot * 2048 + l31 * 64;
#pragma unroll
    for (int rr = 0; rr < 16; rr += 4) {
        int d0 = 8 * (rr >> 2) + 4 * hi;
        uint2 pA = {cvtpk(oA[rr], oA[rr + 1]), cvtpk(oA[rr + 2], oA[rr + 3])};
        uint2 pB = {cvtpk(oB[rr], oB[rr + 1]), cvtpk(oB[rr + 2], oB[rr + 3])};
        *(uint2*)&po[d0] = pA;
        *(uint2*)&po[32 + d0] = pB;
    }
    if (hi == 0) {
        part_ml[(size_t)gslot * 64 + l31] = m_run;
        part_ml[(size_t)gslot * 64 + 32 + l31] = l_run;
    }
}

// ---------------- Combine split-KV partials -> ctx (row-major) ----------------
__global__ __launch_bounds__(128) void attn_combine_kernel(const __bf16* __restrict__ part_O,
                                                           const float* __restrict__ part_ml,
                                                           __bf16* __restrict__ ctx) {
    int bh = blockIdx.x, qp = blockIdx.y;
    int b = bh >> 4, h = bh & 15;
    int nch = 1 + (qp >> 5);
    int base = qp < 32 ? qp : 32 + 2 * (qp - 32);
    size_t so = (size_t)bh * 96 + base;
    int t = threadIdx.x;
    int row = t >> 2, dseg = (t & 3) << 4;

    float mv0 = part_ml[so * 64 + row];
    float mv1 = -1e30f;
    if (nch > 1) mv1 = part_ml[(so + 1) * 64 + row];
    float mmax = fmaxf(mv0, mv1);

    float acc[16];
#pragma unroll
    for (int e = 0; e < 16; ++e) acc[e] = 0.f;
    float lsum = 0.f;

#pragma unroll 2
    for (int i = 0; i < 2; ++i) {
        if (i >= nch) break;
        float mi = i == 0 ? mv0 : mv1;
        float wsc = fexp2(mi - mmax);
        lsum += wsc * part_ml[(so + i) * 64 + 32 + row];
        const __bf16* po = part_O + (so + i) * 2048 + row * 64 + dseg;
        bf16x8 a = *(const bf16x8*)po;
        bf16x8 b2 = *(const bf16x8*)(po + 8);
#pragma unroll
        for (int e = 0; e < 8; ++e) {
            acc[e] += wsc * (float)a[e];
            acc[8 + e] += wsc * (float)b2[e];
        }
    }

    float inv = 1.0f / lsum;
    bf16x8 oa, ob;
#pragma unroll
    for (int e = 0; e < 8; ++e) {
        oa[e] = (__bf16)(acc[e] * inv);
        ob[e] = (__bf16)(acc[8 + e] * inv);
    }
    size_t off = ((size_t)(b * SEQ) + qp * 32 + row) * DIM + h * HD + dseg;
    *(bf16x8*)&ctx[off] = oa;
    *(bf16x8*)&ctx[off + 8] = ob;
}

extern "C" void kernel_launch(void* const* d_in, const int* in_sizes, int n_in,
                              void* d_out, int out_size, void* d_ws, size_t ws_size,
                              hipStream_t stream) {
    const float* x = (const float*)d_in[0];
    const float* w_norm = (const float*)d_in[1];
    const float* Wq = (const float*)d_in[2];
    const float* Wk = (const float*)d_in[3];
    const float* Wv = (const float*)d_in[4];
    const float* Wo = (const float*)d_in[5];
    float* out = (float*)d_out;
    char* w8 = (char*)d_ws;

    const size_t MB = 1ull << 20;
    // [0,8): xn; [8,14): wtq/wtk/wtv — dead after QKV GEMM, reused for partials.
    __bf16* xn = (__bf16*)(w8);
    __bf16* wtq = (__bf16*)(w8 + 8 * MB);
    __bf16* wtk = (__bf16*)(w8 + 10 * MB);
    __bf16* wtv = (__bf16*)(w8 + 12 * MB);
    __bf16* part_O = (__bf16*)(w8);            // 3072 slots * 4KB = 12 MB [0,12)
    float* part_ml = (float*)(w8 + 12 * MB);   // 768 KB [12,12.75)
    __bf16* wto = (__bf16*)(w8 + 14 * MB);     // [14,16)
    __bf16* qf = (__bf16*)(w8 + 16 * MB);      // [16,24) fragment-major Q
    __bf16* kf = (__bf16*)(w8 + 24 * MB);      // [24,32) fragment-major K
    __bf16* vf = (__bf16*)(w8 + 32 * MB);      // [32,40) fragment-major V^T
    __bf16* ctx = (__bf16*)(w8 + 40 * MB);     // [40,48) row-major context
    float* cosT = (float*)(w8 + 48 * MB);      // 256 KB
    float* sinT = cosT + SEQ * 32;             // 256 KB

    wcvt_kernel<<<dim3(32, 32, 4), 256, 0, stream>>>(Wq, Wk, Wv, Wo, wtq, wtk, wtv, wto);
    rmsnorm_bf16<<<ROWS, 256, 0, stream>>>(x, w_norm, xn);
    rope_table_kernel<<<(SEQ * 32) / 256, 256, 0, stream>>>(cosT, sinT);

    gemm_qkv_kernel<<<768, 256, 0, stream>>>(xn, wtq, wtk, wtv, qf, kf, vf, cosT, sinT);

    attn_mfma_kernel<<<dim3(BATCH * NHEADS, 24), 256, 0, stream>>>(qf, kf, vf, part_O, part_ml);
    attn_combine_kernel<<<dim3(BATCH * NHEADS, SEQ / 32), 128, 0, stream>>>(part_O, part_ml, ctx);

    gemm_out_kernel<<<256, 256, 0, stream>>>(ctx, wto, out);
}